// Round 11
// baseline (275.076 us; speedup 1.0000x reference)
//
#include <hip/hip_runtime.h>
#include <hip/hip_bf16.h>

#define CCH 64
#define KOFF 27
#define EPSV 1e-5f

typedef short bf16x8 __attribute__((ext_vector_type(8)));
typedef float f32x4  __attribute__((ext_vector_type(4)));

__device__ __forceinline__ void gld16(const void* g, void* l) {
    __builtin_amdgcn_global_load_lds((const __attribute__((address_space(1))) void*)g,
                                     (__attribute__((address_space(3))) void*)l, 16, 0, 0);
}

// --- fused pre-pass: blocks [0,54) pack W images; blocks [54,..) stats(x).
// W[k][c][d] fp32 -> fragment-order bf16 image (validated r7/r9):
// elem e: p=e>>3, j=e&7; p=((n*2+half)*4+chunk)*16+col16;
// value = W[k][c=chunk*8+half*32+j][d=n*16+col16]
__global__ __launch_bounds__(256) void k_pre(const float* __restrict__ W1,
                                             const float* __restrict__ W2,
                                             __hip_bfloat16* __restrict__ img1,
                                             __hip_bfloat16* __restrict__ img2,
                                             const float* __restrict__ x, int N,
                                             float* __restrict__ sum,
                                             float* __restrict__ sumsq) {
    if (blockIdx.x < 2 * KOFF) {
        int k = blockIdx.x;
        const float* W = W1; __hip_bfloat16* img = img1;
        if (k >= KOFF) { k -= KOFF; W = W2; img = img2; }
        const float* src = W + (size_t)k * CCH * CCH;
        __hip_bfloat16* dst = img + (size_t)k * CCH * CCH;
        for (int e = threadIdx.x; e < CCH * CCH; e += 256) {
            const int p = e >> 3, j = e & 7;
            const int n = p >> 7, half = (p >> 6) & 1, chunk = (p >> 4) & 3, col = p & 15;
            dst[e] = __float2bfloat16(src[(chunk * 8 + half * 32 + j) * CCH + n * 16 + col]);
        }
        return;
    }
    const int bid = blockIdx.x - 2 * KOFF;
    const int nb  = gridDim.x - 2 * KOFF;
    const int c4  = threadIdx.x & 15;
    const int rg  = threadIdx.x >> 4;
    f32x4 s = {0.f, 0.f, 0.f, 0.f}, s2 = {0.f, 0.f, 0.f, 0.f};
    for (int r = bid * 16 + rg; r < N; r += nb * 16) {
        const float4 v = ((const float4*)x)[(size_t)r * 16 + c4];
        s[0] += v.x; s[1] += v.y; s[2] += v.z; s[3] += v.w;
        s2[0] += v.x * v.x; s2[1] += v.y * v.y; s2[2] += v.z * v.z; s2[3] += v.w * v.w;
    }
    __shared__ float sh[2][16][64];
#pragma unroll
    for (int j = 0; j < 4; ++j) {
        sh[0][rg][c4 * 4 + j] = s[j];
        sh[1][rg][c4 * 4 + j] = s2[j];
    }
    __syncthreads();
    if (threadIdx.x < 128) {
        const int which = threadIdx.x >> 6;
        const int c     = threadIdx.x & 63;
        float a = 0.f;
#pragma unroll
        for (int g = 0; g < 16; ++g) a += sh[which][g][c];
        atomicAdd(which ? &sumsq[c] : &sum[c], a);
    }
}

// ---------------- fused BN+ReLU+gather MFMA conv, 128 pts/block (4w x 32).
// A rows gathered RAW from src (f32 or bf16), BN+ReLU applied in-register,
// zero rows (idx==N, ~93%) never loaded; per-16-row-frag ballot skips dead
// MFMA groups (~44%). W pair-staged in LDS (1 barrier / 2 k). Optional fused
// output stats (for next BN); optional residual; dst f32 or bf16.
__global__ __launch_bounds__(256, 3) void k_conv_fused(
        const void* __restrict__ src, int src_f32,
        const int* __restrict__ kmap,
        const __hip_bfloat16* __restrict__ Wimg,
        const float* __restrict__ bn_sum, const float* __restrict__ bn_sq,
        const float* __restrict__ gamma, const float* __restrict__ beta,
        const float* __restrict__ resid,
        void* __restrict__ dst, int dst_f32, int N,
        float* __restrict__ stat_sum, float* __restrict__ stat_sq) {
    __shared__ int sidx[128 * KOFF];              // 13824 B
    __shared__ __hip_bfloat16 wbuf[2][2][4096];   // 2 pairs x 2 slices x 8KB
    __shared__ float st[2][64];

    const int t     = threadIdx.x;
    const int lane  = t & 63;
    const int wave  = t >> 6;
    const int col16 = lane & 15;
    const int chunk = lane >> 4;
    const int base  = blockIdx.x * 128;
    const int p0    = base + wave * 32;

    const long gbase = (long)base * KOFF;
    const long glim  = (long)N * KOFF;
    for (int j = t; j < 128 * KOFF; j += 256)
        sidx[j] = (gbase + j < glim) ? kmap[gbase + j] : N;

    // stage pair 0 (k=0,1): linear lane x 16B dests
    {
        const __hip_bfloat16* g = Wimg + t * 8;
        gld16(g,             &wbuf[0][0][t * 8]);
        gld16(g + 2048,      &wbuf[0][0][t * 8 + 2048]);
        gld16(g + 4096,      &wbuf[0][1][t * 8]);
        gld16(g + 6144,      &wbuf[0][1][t * 8 + 2048]);
    }

    // BN coefficients for this lane's 16 channels (latency hides under staging)
    const float invN = 1.0f / (float)N;
    float scv[16], shv[16];
#pragma unroll
    for (int j = 0; j < 8; ++j) {
        int c = chunk * 8 + j;
        float m = bn_sum[c] * invN, vr = bn_sq[c] * invN - m * m;
        float s = gamma[c] * rsqrtf(vr + EPSV);
        scv[j] = s; shv[j] = beta[c] - m * s;
        c += 32;
        m = bn_sum[c] * invN; vr = bn_sq[c] * invN - m * m;
        s = gamma[c] * rsqrtf(vr + EPSV);
        scv[8 + j] = s; shv[8 + j] = beta[c] - m * s;
    }

    __syncthreads();   // sidx + wbuf[0] ready

    const int r0l = wave * 32 + col16;   // local row, frag m=0
    const int r1l = r0l + 16;            // frag m=1

    f32x4 acc0[4] = {}, acc1[4] = {};

    auto loadraw = [&](int idx, f32x4* raw) {
        if (src_f32) {
            const f32x4* p = (const f32x4*)src + (size_t)idx * 16 + chunk * 2;
            raw[0] = p[0]; raw[1] = p[1]; raw[2] = p[8]; raw[3] = p[9];
        } else {
            const bf16x8* p = (const bf16x8*)src + (size_t)idx * 8 + chunk;
            const bf16x8 s0 = p[0], s1 = p[4];
            float* r = (float*)raw;
#pragma unroll
            for (int j = 0; j < 8; ++j) {
                r[j]     = __builtin_bit_cast(float, (unsigned)((unsigned short)s0[j]) << 16);
                r[8 + j] = __builtin_bit_cast(float, (unsigned)((unsigned short)s1[j]) << 16);
            }
        }
    };
    auto bnpack = [&](const f32x4* raw, bool hh, bf16x8& A0, bf16x8& A1) {
        const float* r = (const float*)raw;
        union { __hip_bfloat16 b[8]; bf16x8 v; } u0, u1;
#pragma unroll
        for (int j = 0; j < 8; ++j) {
            float t0 = r[j] * scv[j] + shv[j];
            float t1 = r[8 + j] * scv[8 + j] + shv[8 + j];
            t0 = (hh && t0 > 0.f) ? t0 : 0.f;
            t1 = (hh && t1 > 0.f) ? t1 : 0.f;
            u0.b[j] = __float2bfloat16(t0);
            u1.b[j] = __float2bfloat16(t1);
        }
        A0 = u0.v; A1 = u1.v;
    };
    auto dok = [&](int k, int buf, int sub) {
        const int i0 = sidx[r0l * KOFF + k];
        const int i1 = sidx[r1l * KOFF + k];
        const bool h0 = (i0 != N), h1 = (i1 != N);
        const unsigned long long b0 = __ballot(h0 ? 1 : 0);
        const unsigned long long b1 = __ballot(h1 ? 1 : 0);
        if (!(b0 | b1)) return;                       // whole k dead for this wave
        f32x4 raw0[4], raw1[4];
        if (h0) loadraw(i0, raw0);
        if (h1) loadraw(i1, raw1);
        const bf16x8* bp = (const bf16x8*)&wbuf[buf][sub][0] + lane;
        bf16x8 B0[4], B1[4];
#pragma unroll
        for (int n = 0; n < 4; ++n) { B0[n] = bp[(2 * n) * 64]; B1[n] = bp[(2 * n + 1) * 64]; }
        if (b0) {
            bf16x8 A0, A1; bnpack(raw0, h0, A0, A1);
#pragma unroll
            for (int n = 0; n < 4; ++n) {
                acc0[n] = __builtin_amdgcn_mfma_f32_16x16x32_bf16(A0, B0[n], acc0[n], 0, 0, 0);
                acc0[n] = __builtin_amdgcn_mfma_f32_16x16x32_bf16(A1, B1[n], acc0[n], 0, 0, 0);
            }
        }
        if (b1) {
            bf16x8 A0, A1; bnpack(raw1, h1, A0, A1);
#pragma unroll
            for (int n = 0; n < 4; ++n) {
                acc1[n] = __builtin_amdgcn_mfma_f32_16x16x32_bf16(A0, B0[n], acc1[n], 0, 0, 0);
                acc1[n] = __builtin_amdgcn_mfma_f32_16x16x32_bf16(A1, B1[n], acc1[n], 0, 0, 0);
            }
        }
    };

    for (int P = 0; 2 * P < KOFF; ++P) {
        const int kA = 2 * P, kB = kA + 1, buf = P & 1;
        if (kA + 2 < KOFF) {                 // stage next pair into other buffer
            const __hip_bfloat16* g = Wimg + (size_t)(kA + 2) * 4096 + t * 8;
            gld16(g,        &wbuf[buf ^ 1][0][t * 8]);
            gld16(g + 2048, &wbuf[buf ^ 1][0][t * 8 + 2048]);
            if (kA + 3 < KOFF) {
                gld16(g + 4096, &wbuf[buf ^ 1][1][t * 8]);
                gld16(g + 6144, &wbuf[buf ^ 1][1][t * 8 + 2048]);
            }
        }
        dok(kA, buf, 0);
        if (kB < KOFF) dok(kB, buf, 1);
        __syncthreads();   // waves done with wbuf[buf]; drains staging loads
    }

    if (stat_sum) {
        if (t < 128) st[t >> 6][t & 63] = 0.0f;
        __syncthreads();
    }

    float* dstf = (float*)dst;
    __hip_bfloat16* dstb = (__hip_bfloat16*)dst;
    // D layout: col = lane&15, row = chunk*4 + reg  [validated r3/r7/r9]
#pragma unroll
    for (int m = 0; m < 2; ++m) {
#pragma unroll
        for (int n = 0; n < 4; ++n) {
            const int col = n * 16 + col16;
            float s = 0.f, s2 = 0.f;
#pragma unroll
            for (int j = 0; j < 4; ++j) {
                const int row = p0 + m * 16 + chunk * 4 + j;
                if (row < N) {
                    float v = (m == 0 ? acc0[n][j] : acc1[n][j]);
                    if (resid) v += resid[(size_t)row * CCH + col];
                    if (dst_f32) dstf[(size_t)row * CCH + col] = v;
                    else         dstb[(size_t)row * CCH + col] = __float2bfloat16(v);
                    s += v; s2 += v * v;
                }
            }
            if (stat_sum) {
                atomicAdd(&st[0][col], s);
                atomicAdd(&st[1][col], s2);
            }
        }
    }
    if (stat_sum) {
        __syncthreads();
        if (t < 64)       atomicAdd(&stat_sum[t], st[0][t]);
        else if (t < 128) atomicAdd(&stat_sq[t - 64], st[1][t - 64]);
    }
}

// ---------------------------------------------------------------- launcher
extern "C" void kernel_launch(void* const* d_in, const int* in_sizes, int n_in,
                              void* d_out, int out_size, void* d_ws, size_t ws_size,
                              hipStream_t stream) {
    const float* x      = (const float*)d_in[0];
    const int*   kmap   = (const int*)d_in[1];
    const float* gamma1 = (const float*)d_in[2];
    const float* beta1  = (const float*)d_in[3];
    const float* W1     = (const float*)d_in[4];
    const float* gamma2 = (const float*)d_in[5];
    const float* beta2  = (const float*)d_in[6];
    const float* W2     = (const float*)d_in[7];
    float*       out    = (float*)d_out;

    const int N = in_sizes[0] / CCH;  // 100000

    // ws layout: stats(1KB) | img1 | img2 | h1 (f32 if it fits, else bf16)
    char* wp = (char*)d_ws;
    float*          stats = (float*)wp;              wp += 1024;
    __hip_bfloat16* img1  = (__hip_bfloat16*)wp;     wp += (size_t)KOFF * CCH * CCH * 2;
    __hip_bfloat16* img2  = (__hip_bfloat16*)wp;     wp += (size_t)KOFF * CCH * CCH * 2;
    const size_t head = (size_t)(wp - (char*)d_ws);
    const int h1_f32 = (ws_size >= head + (size_t)N * CCH * 4) ? 1 : 0;
    void* h1 = (void*)wp;

    hipMemsetAsync(stats, 0, 1024, stream);
    k_pre<<<2 * KOFF + 512, 256, 0, stream>>>(W1, W2, img1, img2, x, N,
                                              stats + 0, stats + 64);

    const int cgrid = (N + 127) / 128;

    // conv1: src=x (f32) -> BN1+ReLU in-reg -> conv(W1) -> h1; fused BN2 stats
    k_conv_fused<<<cgrid, 256, 0, stream>>>(x, 1, kmap, img1,
                                            stats + 0, stats + 64, gamma1, beta1,
                                            nullptr, h1, h1_f32, N,
                                            stats + 128, stats + 192);

    // conv2: src=h1 -> BN2+ReLU in-reg -> conv(W2) + residual(x) -> d_out
    k_conv_fused<<<cgrid, 256, 0, stream>>>(h1, h1_f32, kmap, img2,
                                            stats + 128, stats + 192, gamma2, beta2,
                                            x, out, 1, N,
                                            nullptr, nullptr);
}